// Round 6
// baseline (221.165 us; speedup 1.0000x reference)
//
#include <hip/hip_runtime.h>
#include <cstdint>
#include <cstddef>

#define NB 2
#define NN 4096
#define ND 256
#define TRI 528   // 32*33/2 causal 128-tiles per (batch, mat)

typedef __attribute__((ext_vector_type(8))) _Float16 half8;
typedef __attribute__((ext_vector_type(4))) _Float16 half4;
typedef __attribute__((ext_vector_type(4))) float f32x4;

using gas_ptr = const __attribute__((address_space(1))) void*;
using las_ptr = __attribute__((address_space(3))) void*;

__device__ __host__ __forceinline__ int tri32(int t) { return t * (t + 1) / 2; }

__device__ __forceinline__ f32x4 mfma_16x16x32(half8 a, half8 b, f32x4 c) {
    return __builtin_amdgcn_mfma_f32_16x16x32_f16(a, b, c, 0, 0, 0);
}

// ---------------- conversions ----------------
__global__ __launch_bounds__(256) void k_cvt_h(const float* __restrict__ h,
                                               _Float16* __restrict__ h16) {
    const int i = blockIdx.x * 256 + threadIdx.x;
    f32x4 v = ((const f32x4*)h)[i];
    half4 o;
    o[0] = (_Float16)v[0]; o[1] = (_Float16)v[1];
    o[2] = (_Float16)v[2]; o[3] = (_Float16)v[3];
    ((half4*)h16)[i] = o;
}

__global__ __launch_bounds__(256) void k_wt(const float* __restrict__ W0, const float* __restrict__ W1,
                                            const float* __restrict__ W2, const float* __restrict__ W3,
                                            _Float16* __restrict__ T0, _Float16* __restrict__ T1,
                                            _Float16* __restrict__ T2, _Float16* __restrict__ T3) {
    const int m = blockIdx.y;
    const float* W = m == 0 ? W0 : m == 1 ? W1 : m == 2 ? W2 : W3;
    _Float16* T    = m == 0 ? T0 : m == 1 ? T1 : m == 2 ? T2 : T3;
    const int k = blockIdx.x, j = threadIdx.x;
    T[j * ND + k] = (_Float16)W[k * ND + j];
}

// ---------------- GEMM core (projections / output) ----------------
__device__ __forceinline__ void gemm_core(const _Float16* __restrict__ A,
                                          const _Float16* __restrict__ Bt,
                                          int row0, int l16, int lg, f32x4 acc[16]) {
    #pragma unroll
    for (int i = 0; i < 16; ++i) acc[i] = (f32x4)0.0f;
    #pragma unroll
    for (int ks = 0; ks < 8; ++ks) {
        half8 a = *(const half8*)(A + (size_t)(row0 + l16) * ND + ks * 32 + lg * 8);
        #pragma unroll
        for (int ct = 0; ct < 16; ++ct) {
            half8 b = *(const half8*)(Bt + (size_t)(ct * 16 + l16) * ND + ks * 32 + lg * 8);
            acc[ct] = mfma_16x16x32(a, b, acc[ct]);
        }
    }
}

__global__ __launch_bounds__(256) void k_proj(const _Float16* __restrict__ h16,
                                              const _Float16* __restrict__ Wlt,
                                              const _Float16* __restrict__ Wgt,
                                              const _Float16* __restrict__ Wvt,
                                              _Float16* __restrict__ zn,
                                              _Float16* __restrict__ zg,
                                              _Float16* __restrict__ v16,
                                              float* __restrict__ sq) {
    const int mode = blockIdx.y;
    const _Float16* Bt = mode == 0 ? Wlt : mode == 1 ? Wgt : Wvt;
    _Float16* o16      = mode == 0 ? zn  : mode == 1 ? zg  : v16;
    const int w = threadIdx.x >> 6, l = threadIdx.x & 63;
    const int l16 = l & 15, lg = l >> 4;
    const int row0 = blockIdx.x * 64 + w * 16;
    f32x4 acc[16];
    gemm_core(h16, Bt, row0, l16, lg, acc);

    if (mode == 2) {
        #pragma unroll
        for (int ct = 0; ct < 16; ++ct)
            #pragma unroll
            for (int r = 0; r < 4; ++r)
                o16[(size_t)(row0 + lg * 4 + r) * ND + ct * 16 + l16] = (_Float16)acc[ct][r];
        return;
    }
    float n2[4] = {0.f, 0.f, 0.f, 0.f};
    #pragma unroll
    for (int ct = 0; ct < 16; ++ct)
        #pragma unroll
        for (int r = 0; r < 4; ++r) n2[r] += acc[ct][r] * acc[ct][r];
    #pragma unroll
    for (int m = 1; m < 16; m <<= 1) {
        #pragma unroll
        for (int r = 0; r < 4; ++r) n2[r] += __shfl_xor(n2[r], m);
    }
    if (mode == 0) {
        float ri[4];
        #pragma unroll
        for (int r = 0; r < 4; ++r) ri[r] = 1.0f / fmaxf(sqrtf(n2[r]), 1e-8f);
        #pragma unroll
        for (int ct = 0; ct < 16; ++ct)
            #pragma unroll
            for (int r = 0; r < 4; ++r)
                o16[(size_t)(row0 + lg * 4 + r) * ND + ct * 16 + l16] =
                    (_Float16)(acc[ct][r] * ri[r]);
    } else {
        #pragma unroll
        for (int ct = 0; ct < 16; ++ct)
            #pragma unroll
            for (int r = 0; r < 4; ++r)
                o16[(size_t)(row0 + lg * 4 + r) * ND + ct * 16 + l16] = (_Float16)acc[ct][r];
        if (l16 == 0) {
            #pragma unroll
            for (int r = 0; r < 4; ++r) sq[row0 + lg * 4 + r] = n2[r];
        }
    }
}

// v16 [b][n][d] -> vT [b][d][n]
__global__ __launch_bounds__(256) void k_tr(const _Float16* __restrict__ v16,
                                            _Float16* __restrict__ vT) {
    __shared__ _Float16 t[64][72];
    const int b = blockIdx.z, n0 = blockIdx.x * 64, d0 = blockIdx.y * 64;
    const int tj = threadIdx.x & 63, ti = threadIdx.x >> 6;
    #pragma unroll
    for (int i = 0; i < 16; ++i)
        t[ti + i * 4][tj] = v16[(size_t)(b * NN + n0 + ti + i * 4) * ND + d0 + tj];
    __syncthreads();
    #pragma unroll
    for (int i = 0; i < 16; ++i)
        vT[(size_t)(b * ND + d0 + ti + i * 4) * NN + n0 + tj] = t[tj][ti + i * 4];
}

// ---------------- score GEMM v2: 4 tiles/block, 16 pipelined steps ----------------
// grid 528 = (NB*2 mats) * 132; each block owns 4 consecutive causal tiles.
// Per step (BK=64): stage(j+1) -> buf^1 (global_load_lds, swizzled src), compute
// step j from buf (2 kst x 16 MFMA / wave), epilogue every 4th step, ONE barrier.
__global__ __launch_bounds__(256, 2) void k_score(const _Float16* __restrict__ zn,
                                                  const _Float16* __restrict__ zg,
                                                  const float* __restrict__ sqg,
                                                  _Float16* __restrict__ P,
                                                  float* __restrict__ degpart) {
    const int bm = blockIdx.x / 132;          // b*2 + mat
    const int b = bm >> 1, mat = bm & 1;
    const int tile0 = (blockIdx.x % 132) * 4;
    const char* z = (const char*)((mat ? zg : zn) + (size_t)b * NN * ND);
    const float* sqb = sqg + (size_t)b * NN;

    const int w = threadIdx.x >> 6, lane = threadIdx.x & 63;
    const int l16 = lane & 15, lg = lane >> 4;
    const int wr = w >> 1, wc = w & 1;

    __shared__ char At[2][16384], Bq[2][16384];

    int g_tq = 0, g_tk = tile0;               // stage cursor (decode tile0)
    while (g_tk > g_tq) { g_tk -= (g_tq + 1); ++g_tq; }
    int c_tq = g_tq, c_tk = g_tk;             // compute cursor

    auto STAGE = [&](int bufi, int tq_, int tk_, int s_) {
        const int off = threadIdx.x * 16;
        #pragma unroll
        for (int i = 0; i < 4; ++i) {
            const int o = off + i * 4096;
            const int row = o >> 7;
            const int sx = (o & 127) ^ ((row & 7) << 4);
            __builtin_amdgcn_global_load_lds(
                (gas_ptr)(z + (size_t)(tk_ * 128 + row) * 512 + s_ * 128 + sx),
                (las_ptr)(&At[bufi][0] + o), 16, 0, 0);
        }
        #pragma unroll
        for (int i = 0; i < 4; ++i) {
            const int o = off + i * 4096;
            const int row = o >> 7;
            const int sx = (o & 127) ^ ((row & 7) << 4);
            __builtin_amdgcn_global_load_lds(
                (gas_ptr)(z + (size_t)(tq_ * 128 + row) * 512 + s_ * 128 + sx),
                (las_ptr)(&Bq[bufi][0] + o), 16, 0, 0);
        }
    };

    f32x4 acc[4][4];
    #pragma unroll
    for (int i = 0; i < 4; ++i)
        #pragma unroll
        for (int j = 0; j < 4; ++j) acc[i][j] = (f32x4)0.f;

    STAGE(0, g_tq, g_tk, 0);
    __syncthreads();

    for (int j = 0; j < 16; ++j) {
        // issue next stage first (full compute phase of latency cover)
        if (j + 1 < 16) {
            if (((j + 1) & 3) == 0) { ++g_tk; if (g_tk > g_tq) { g_tk = 0; ++g_tq; } }
            STAGE((j + 1) & 1, g_tq, g_tk, (j + 1) & 3);
        }
        const int cb = j & 1;
        #pragma unroll
        for (int kst = 0; kst < 2; ++kst) {
            half8 a[4], bq[4];
            #pragma unroll
            for (int i = 0; i < 4; ++i) {
                const int ar = wr * 64 + i * 16 + l16;
                a[i] = *(const half8*)(&At[cb][0] + ar * 128 + ((kst * 64 + lg * 16) ^ ((ar & 7) << 4)));
                const int br = wc * 64 + i * 16 + l16;
                bq[i] = *(const half8*)(&Bq[cb][0] + br * 128 + ((kst * 64 + lg * 16) ^ ((br & 7) << 4)));
            }
            #pragma unroll
            for (int di = 0; di < 4; ++di)
                #pragma unroll
                for (int qi = 0; qi < 4; ++qi)
                    acc[di][qi] = mfma_16x16x32(a[di], bq[qi], acc[di][qi]);
        }
        if ((j & 3) == 3) {
            // ---- epilogue for tile (c_tq, c_tk): transform, P write, degree partials
            const int tile = tri32(c_tq) + c_tk;
            _Float16* Pt = P + (size_t)(bm * TRI + tile) * 16384;
            float dsum[4] = {0.f, 0.f, 0.f, 0.f};
            float sqq[4];
            if (mat) {
                #pragma unroll
                for (int qi = 0; qi < 4; ++qi)
                    sqq[qi] = sqb[c_tq * 128 + wc * 64 + qi * 16 + l16];
            }
            #pragma unroll
            for (int di = 0; di < 4; ++di) {
                const int kl = wr * 64 + di * 16 + lg * 4;
                const int kg = c_tk * 128 + kl;
                f32x4 sqk;
                if (mat) sqk = *(const f32x4*)(sqb + kg);
                #pragma unroll
                for (int qi = 0; qi < 4; ++qi) {
                    const int qg = c_tq * 128 + wc * 64 + qi * 16 + l16;
                    half4 hv;
                    #pragma unroll
                    for (int r = 0; r < 4; ++r) {
                        const bool msk = (kg + r) < qg;        // causal + zero-diag
                        float p;
                        if (mat) p = msk ? __expf(-0.5f * (sqq[qi] + sqk[r] - 2.f * acc[di][qi][r])) : 0.f;
                        else     p = msk ? fmaxf(acc[di][qi][r], 0.f) : 0.f;
                        dsum[qi] += p;
                        hv[r] = (_Float16)p;
                    }
                    *(half4*)(Pt + (size_t)(wc * 64 + qi * 16 + l16) * 128 + kl) = hv;
                    acc[di][qi] = (f32x4)0.f;
                }
            }
            #pragma unroll
            for (int qi = 0; qi < 4; ++qi) {
                dsum[qi] += __shfl_xor(dsum[qi], 16);
                dsum[qi] += __shfl_xor(dsum[qi], 32);
            }
            if (lg == 0) {
                #pragma unroll
                for (int qi = 0; qi < 4; ++qi)
                    degpart[(size_t)(bm * TRI + tile) * 256 + wr * 128 + wc * 64 + qi * 16 + l16] = dsum[qi];
            }
            ++c_tk; if (c_tk > c_tq) { c_tk = 0; ++c_tq; }
        }
        __syncthreads();
    }
}

// ---------------- deg: sum tile/wave partials (deterministic) ----------------
__global__ __launch_bounds__(128) void k_deg(const float* __restrict__ degpart,
                                             float* __restrict__ deg) {
    const int bm = blockIdx.x >> 5, tq = blockIdx.x & 31;
    const float* dp = degpart + (size_t)(bm * TRI + tri32(tq)) * 256 + threadIdx.x;
    float s = 0.f;
    for (int tk = 0; tk <= tq; ++tk)
        s += dp[(size_t)tk * 256] + dp[(size_t)tk * 256 + 128];
    deg[(size_t)bm * NN + tq * 128 + threadIdx.x] = s;
}

// ---------------- PV GEMM v2: O^T = V^T P^T, split-K, pipelined steps ----------------
// grid.x item = chunk*4 + mat*2 + dh (reversed -> longest chunks first).
// Steps = 2*(ktE-kt0): stage(j+1) at top, compute j, ONE barrier per step.
__global__ __launch_bounds__(256, 2) void k_pv(const _Float16* __restrict__ P,
                                               const _Float16* __restrict__ vT,
                                               _Float16* __restrict__ part,
                                               int CHUNK, int NCH) {
    const int dh = blockIdx.x & 1, mat = (blockIdx.x >> 1) & 1;
    int x = NCH - 1 - (blockIdx.x >> 2);     // reversed: long chunks dispatch first
    int tq = 0, cum = 0;
    for (;;) {
        const int nc = (tq + CHUNK) / CHUNK;  // ceil((tq+1)/CHUNK)
        if (x < nc) break;
        x -= nc; cum += nc; ++tq;
    }
    const int c = x;
    const int b = blockIdx.y;
    const int kt0 = c * CHUNK;
    const int ktE = (kt0 + CHUNK < tq + 1) ? kt0 + CHUNK : tq + 1;
    const int NS = (ktE - kt0) * 2;

    const int w = threadIdx.x >> 6, lane = threadIdx.x & 63;
    const int l16 = lane & 15, lg = lane >> 4;
    const int wr = w >> 1, wc = w & 1;

    __shared__ char At[2][16384], Bp[2][16384];

    const char* vTb = (const char*)(vT + (size_t)b * ND * NN);
    const char* Pbase = (const char*)(P + (size_t)((b * 2 + mat) * TRI + tri32(tq)) * 16384);

    auto STAGE = [&](int bufi, int j_) {
        const int kt = kt0 + (j_ >> 1), s = j_ & 1;
        const char* Pt = Pbase + (size_t)kt * 32768;
        const int off = threadIdx.x * 16;
        #pragma unroll
        for (int i = 0; i < 4; ++i) {
            const int o = off + i * 4096;
            const int row = o >> 7;
            const int sx = (o & 127) ^ ((row & 7) << 4);
            __builtin_amdgcn_global_load_lds(
                (gas_ptr)(vTb + (size_t)(dh * 128 + row) * (NN * 2) + (size_t)kt * 256 + s * 128 + sx),
                (las_ptr)(&At[bufi][0] + o), 16, 0, 0);
        }
        #pragma unroll
        for (int i = 0; i < 4; ++i) {
            const int o = off + i * 4096;
            const int row = o >> 7;
            const int sx = (o & 127) ^ ((row & 7) << 4);
            __builtin_amdgcn_global_load_lds(
                (gas_ptr)(Pt + (size_t)row * 256 + s * 128 + sx),
                (las_ptr)(&Bp[bufi][0] + o), 16, 0, 0);
        }
    };

    f32x4 acc[4][4];
    #pragma unroll
    for (int i = 0; i < 4; ++i)
        #pragma unroll
        for (int j = 0; j < 4; ++j) acc[i][j] = (f32x4)0.f;

    STAGE(0, 0);
    __syncthreads();

    for (int j = 0; j < NS; ++j) {
        if (j + 1 < NS) STAGE((j + 1) & 1, j + 1);
        const int cb = j & 1;
        #pragma unroll
        for (int kst = 0; kst < 2; ++kst) {
            half8 a[4], bp[4];
            #pragma unroll
            for (int i = 0; i < 4; ++i) {
                const int ar = wr * 64 + i * 16 + l16;
                a[i] = *(const half8*)(&At[cb][0] + ar * 128 + ((kst * 64 + lg * 16) ^ ((ar & 7) << 4)));
                const int br = wc * 64 + i * 16 + l16;
                bp[i] = *(const half8*)(&Bp[cb][0] + br * 128 + ((kst * 64 + lg * 16) ^ ((br & 7) << 4)));
            }
            #pragma unroll
            for (int di = 0; di < 4; ++di)
                #pragma unroll
                for (int qi = 0; qi < 4; ++qi)
                    acc[di][qi] = mfma_16x16x32(a[di], bp[qi], acc[di][qi]);
        }
        __syncthreads();
    }

    _Float16* sl = part + (size_t)(((b * NCH + cum + c) * 2 + dh) * 2 + mat) * 16384;
    #pragma unroll
    for (int di = 0; di < 4; ++di) {
        const int dl = wr * 64 + di * 16 + lg * 4;
        #pragma unroll
        for (int qi = 0; qi < 4; ++qi) {
            half4 hv;
            #pragma unroll
            for (int r = 0; r < 4; ++r) hv[r] = (_Float16)acc[di][qi][r];
            *(half4*)(sl + (size_t)(wc * 64 + qi * 16 + l16) * 128 + dl) = hv;
        }
    }
}

// ---------------- combine chunk partials, normalize, emit ot ----------------
__global__ __launch_bounds__(256) void k_combine2(const _Float16* __restrict__ part,
                                                  const float* __restrict__ deg,
                                                  _Float16* __restrict__ ot,
                                                  int CHUNK, int NCH) {
    const int tq = blockIdx.x >> 1, dh = blockIdx.x & 1, b = blockIdx.y;
    int cum = 0;
    for (int t = 0; t < tq; ++t) cum += (t + CHUNK) / CHUNK;
    const int nc = (tq + CHUNK) / CHUNK;
    const float* degl = deg + (size_t)(b * 2 + 0) * NN + tq * 128;
    const float* degg = deg + (size_t)(b * 2 + 1) * NN + tq * 128;
    for (int it = 0; it < 8; ++it) {
        const int e = (it * 256 + threadIdx.x) * 8;
        const int row = e >> 7, col = e & 127;
        float s_l[8] = {0,0,0,0,0,0,0,0}, s_g[8] = {0,0,0,0,0,0,0,0};
        for (int c2 = 0; c2 < nc; ++c2) {
            const size_t base = (size_t)(((b * NCH + cum + c2) * 2 + dh) * 2) * 16384 + e;
            half8 xl = *(const half8*)(part + base);
            half8 xg = *(const half8*)(part + base + 16384);
            #pragma unroll
            for (int k = 0; k < 8; ++k) { s_l[k] += (float)xl[k]; s_g[k] += (float)xg[k]; }
        }
        const float rl = 0.9f / fmaxf(degl[row], 1e-8f);   // w_l = 1 - T_WAKE
        const float rg = 0.1f / fmaxf(degg[row], 1e-8f);   // w_g = T_WAKE
        half8 o;
        #pragma unroll
        for (int k = 0; k < 8; ++k) o[k] = (_Float16)(rl * s_l[k] + rg * s_g[k]);
        *(half8*)(ot + (size_t)(b * NN + tq * 128 + row) * ND + dh * 128 + col) = o;
    }
}

// ---------------- final @ Wo ----------------
__global__ __launch_bounds__(256) void k_out(const _Float16* __restrict__ ot,
                                             const _Float16* __restrict__ Wot,
                                             float* __restrict__ out) {
    const int w = threadIdx.x >> 6, l = threadIdx.x & 63;
    const int l16 = l & 15, lg = l >> 4;
    const int row0 = blockIdx.x * 64 + w * 16;
    f32x4 acc[16];
    gemm_core(ot, Wot, row0, l16, lg, acc);
    #pragma unroll
    for (int ct = 0; ct < 16; ++ct)
        #pragma unroll
        for (int r = 0; r < 4; ++r)
            out[(size_t)(row0 + lg * 4 + r) * ND + ct * 16 + l16] = acc[ct][r];
}

extern "C" void kernel_launch(void* const* d_in, const int* in_sizes, int n_in,
                              void* d_out, int out_size, void* d_ws, size_t ws_size,
                              hipStream_t stream) {
    const float* h  = (const float*)d_in[0];
    const float* Wl = (const float*)d_in[2];
    const float* Wg = (const float*)d_in[3];
    const float* Wv = (const float*)d_in[4];
    const float* Wo = (const float*)d_in[5];
    float* out = (float*)d_out;

    uint8_t* base = (uint8_t*)d_ws;
    size_t off = 0;
    auto alloc = [&](size_t bytes) -> void* {
        void* r = base + off;
        off = (off + bytes + 255) & ~(size_t)255;
        return r;
    };
    const size_t bnd = (size_t)NB * NN * ND;
    _Float16* h16 = (_Float16*)alloc(bnd * 2);     // reused as vT after k_proj
    _Float16* Wlt = (_Float16*)alloc(ND * ND * 2);
    _Float16* Wgt = (_Float16*)alloc(ND * ND * 2);
    _Float16* Wvt = (_Float16*)alloc(ND * ND * 2);
    _Float16* Wot = (_Float16*)alloc(ND * ND * 2);
    _Float16* zn  = (_Float16*)alloc(bnd * 2);
    _Float16* zg  = (_Float16*)alloc(bnd * 2);
    _Float16* v16 = (_Float16*)alloc(bnd * 2);
    _Float16* ot  = (_Float16*)alloc(bnd * 2);
    float*    sq  = (float*)alloc((size_t)NB * NN * 4);
    _Float16* P   = (_Float16*)alloc((size_t)NB * 2 * TRI * 16384 * 2);   // 69 MB
    float* degpart = (float*)alloc((size_t)NB * 2 * TRI * 256 * 4);       // 2.2 MB
    float* deg     = (float*)alloc((size_t)NB * 2 * NN * 4);              // 64 KB
    _Float16* vT = h16;                            // alias: h16 dead after k_proj

    // split-K chunking with ws fallback
    int CHUNK = 8, NCH = 0;
    for (;;) {
        NCH = 0;
        for (int t = 0; t < 32; ++t) NCH += (t + CHUNK) / CHUNK;
        if (off + (size_t)NB * NCH * 4 * 16384 * 2 + 256 <= ws_size || CHUNK >= 32) break;
        CHUNK *= 2;
    }
    _Float16* part = (_Float16*)alloc((size_t)NB * NCH * 4 * 16384 * 2);

    k_cvt_h<<<bnd / 4 / 256, 256, 0, stream>>>(h, h16);
    k_wt<<<dim3(ND, 4), 256, 0, stream>>>(Wl, Wg, Wv, Wo, Wlt, Wgt, Wvt, Wot);
    k_proj<<<dim3(NB * NN / 64, 3), 256, 0, stream>>>(h16, Wlt, Wgt, Wvt, zn, zg, v16, sq);
    k_tr<<<dim3(NN / 64, ND / 64, NB), 256, 0, stream>>>(v16, vT);
    k_score<<<dim3(528), 256, 0, stream>>>(zn, zg, sq, P, degpart);
    k_deg<<<NB * 2 * 32, 128, 0, stream>>>(degpart, deg);
    k_pv<<<dim3(4 * NCH, NB), 256, 0, stream>>>(P, vT, part, CHUNK, NCH);
    k_combine2<<<dim3(64, NB), 256, 0, stream>>>(part, deg, ot, CHUNK, NCH);
    k_out<<<NB * NN / 64, 256, 0, stream>>>(ot, Wot, out);
}

// Round 7
// 189.279 us; speedup vs baseline: 1.1685x; 1.1685x over previous
//
#include <hip/hip_runtime.h>
#include <cstdint>
#include <cstddef>

#define NB 2
#define NN 4096
#define ND 256
#define TRI 528   // 32*33/2 causal 128-tiles per (batch, mat)

typedef __attribute__((ext_vector_type(8))) _Float16 half8;
typedef __attribute__((ext_vector_type(4))) _Float16 half4;
typedef __attribute__((ext_vector_type(4))) float f32x4;

using gas_ptr = const __attribute__((address_space(1))) void*;
using las_ptr = __attribute__((address_space(3))) void*;

__device__ __host__ __forceinline__ int tri32(int t) { return t * (t + 1) / 2; }

__device__ __forceinline__ f32x4 mfma_16x16x32(half8 a, half8 b, f32x4 c) {
    return __builtin_amdgcn_mfma_f32_16x16x32_f16(a, b, c, 0, 0, 0);
}

// ---------------- conversions ----------------
__global__ __launch_bounds__(256) void k_cvt_h(const float* __restrict__ h,
                                               _Float16* __restrict__ h16) {
    const int i = blockIdx.x * 256 + threadIdx.x;
    f32x4 v = ((const f32x4*)h)[i];
    half4 o;
    o[0] = (_Float16)v[0]; o[1] = (_Float16)v[1];
    o[2] = (_Float16)v[2]; o[3] = (_Float16)v[3];
    ((half4*)h16)[i] = o;
}

__global__ __launch_bounds__(256) void k_wt(const float* __restrict__ W0, const float* __restrict__ W1,
                                            const float* __restrict__ W2, const float* __restrict__ W3,
                                            _Float16* __restrict__ T0, _Float16* __restrict__ T1,
                                            _Float16* __restrict__ T2, _Float16* __restrict__ T3) {
    const int m = blockIdx.y;
    const float* W = m == 0 ? W0 : m == 1 ? W1 : m == 2 ? W2 : W3;
    _Float16* T    = m == 0 ? T0 : m == 1 ? T1 : m == 2 ? T2 : T3;
    const int k = blockIdx.x, j = threadIdx.x;
    T[j * ND + k] = (_Float16)W[k * ND + j];
}

// ---------------- GEMM core (projections / output) ----------------
__device__ __forceinline__ void gemm_core(const _Float16* __restrict__ A,
                                          const _Float16* __restrict__ Bt,
                                          int row0, int l16, int lg, f32x4 acc[16]) {
    #pragma unroll
    for (int i = 0; i < 16; ++i) acc[i] = (f32x4)0.0f;
    #pragma unroll
    for (int ks = 0; ks < 8; ++ks) {
        half8 a = *(const half8*)(A + (size_t)(row0 + l16) * ND + ks * 32 + lg * 8);
        #pragma unroll
        for (int ct = 0; ct < 16; ++ct) {
            half8 b = *(const half8*)(Bt + (size_t)(ct * 16 + l16) * ND + ks * 32 + lg * 8);
            acc[ct] = mfma_16x16x32(a, b, acc[ct]);
        }
    }
}

__global__ __launch_bounds__(256) void k_proj(const _Float16* __restrict__ h16,
                                              const _Float16* __restrict__ Wlt,
                                              const _Float16* __restrict__ Wgt,
                                              const _Float16* __restrict__ Wvt,
                                              _Float16* __restrict__ zn,
                                              _Float16* __restrict__ zg,
                                              _Float16* __restrict__ v16,
                                              float* __restrict__ sq) {
    const int mode = blockIdx.y;
    const _Float16* Bt = mode == 0 ? Wlt : mode == 1 ? Wgt : Wvt;
    _Float16* o16      = mode == 0 ? zn  : mode == 1 ? zg  : v16;
    const int w = threadIdx.x >> 6, l = threadIdx.x & 63;
    const int l16 = l & 15, lg = l >> 4;
    const int row0 = blockIdx.x * 64 + w * 16;
    f32x4 acc[16];
    gemm_core(h16, Bt, row0, l16, lg, acc);

    if (mode == 2) {
        #pragma unroll
        for (int ct = 0; ct < 16; ++ct)
            #pragma unroll
            for (int r = 0; r < 4; ++r)
                o16[(size_t)(row0 + lg * 4 + r) * ND + ct * 16 + l16] = (_Float16)acc[ct][r];
        return;
    }
    float n2[4] = {0.f, 0.f, 0.f, 0.f};
    #pragma unroll
    for (int ct = 0; ct < 16; ++ct)
        #pragma unroll
        for (int r = 0; r < 4; ++r) n2[r] += acc[ct][r] * acc[ct][r];
    #pragma unroll
    for (int m = 1; m < 16; m <<= 1) {
        #pragma unroll
        for (int r = 0; r < 4; ++r) n2[r] += __shfl_xor(n2[r], m);
    }
    if (mode == 0) {
        float ri[4];
        #pragma unroll
        for (int r = 0; r < 4; ++r) ri[r] = 1.0f / fmaxf(sqrtf(n2[r]), 1e-8f);
        #pragma unroll
        for (int ct = 0; ct < 16; ++ct)
            #pragma unroll
            for (int r = 0; r < 4; ++r)
                o16[(size_t)(row0 + lg * 4 + r) * ND + ct * 16 + l16] =
                    (_Float16)(acc[ct][r] * ri[r]);
    } else {
        #pragma unroll
        for (int ct = 0; ct < 16; ++ct)
            #pragma unroll
            for (int r = 0; r < 4; ++r)
                o16[(size_t)(row0 + lg * 4 + r) * ND + ct * 16 + l16] = (_Float16)acc[ct][r];
        if (l16 == 0) {
            #pragma unroll
            for (int r = 0; r < 4; ++r) sq[row0 + lg * 4 + r] = n2[r];
        }
    }
}

// v16 [b][n][d] -> vT [b][d][n]
__global__ __launch_bounds__(256) void k_tr(const _Float16* __restrict__ v16,
                                            _Float16* __restrict__ vT) {
    __shared__ _Float16 t[64][72];
    const int b = blockIdx.z, n0 = blockIdx.x * 64, d0 = blockIdx.y * 64;
    const int tj = threadIdx.x & 63, ti = threadIdx.x >> 6;
    #pragma unroll
    for (int i = 0; i < 16; ++i)
        t[ti + i * 4][tj] = v16[(size_t)(b * NN + n0 + ti + i * 4) * ND + d0 + tj];
    __syncthreads();
    #pragma unroll
    for (int i = 0; i < 16; ++i)
        vT[(size_t)(b * ND + d0 + ti + i * 4) * NN + n0 + tj] = t[tj][ti + i * 4];
}

// ---------------- score GEMM v3: one 128-tile per block, dbuf, 1 barrier/step ----
// grid (TRI, NB, 2). Per step s (BK=64): STAGE(s+1) -> other buf at top, compute
// step s (2 kst x 16 MFMA/wave), one barrier. Final barrier elided. Epilogue:
// mask + transform, P[q][k] f16 b64 writes, per-wave degree partials.
__global__ __launch_bounds__(256, 2) void k_score(const _Float16* __restrict__ zn,
                                                  const _Float16* __restrict__ zg,
                                                  const float* __restrict__ sqg,
                                                  _Float16* __restrict__ P,
                                                  float* __restrict__ degpart) {
    int x = blockIdx.x, tq = 0;
    while (x > tq) { x -= (tq + 1); ++tq; }
    const int tk = x;
    const int b = blockIdx.y, mat = blockIdx.z;
    const int bm = b * 2 + mat;
    const char* z = (const char*)((mat ? zg : zn) + (size_t)b * NN * ND);
    const float* sqb = sqg + (size_t)b * NN;
    const int w = threadIdx.x >> 6, lane = threadIdx.x & 63;
    const int l16 = lane & 15, lg = lane >> 4;
    const int wr = w >> 1, wc = w & 1;

    __shared__ char At[2][16384], Bq[2][16384];

    auto STAGE = [&](int bufi, int s_) {
        const int off = threadIdx.x * 16;
        #pragma unroll
        for (int i = 0; i < 4; ++i) {
            const int o = off + i * 4096;
            const int row = o >> 7;
            const int sx = (o & 127) ^ ((row & 7) << 4);
            __builtin_amdgcn_global_load_lds(
                (gas_ptr)(z + (size_t)(tk * 128 + row) * 512 + s_ * 128 + sx),
                (las_ptr)(&At[bufi][0] + o), 16, 0, 0);
        }
        #pragma unroll
        for (int i = 0; i < 4; ++i) {
            const int o = off + i * 4096;
            const int row = o >> 7;
            const int sx = (o & 127) ^ ((row & 7) << 4);
            __builtin_amdgcn_global_load_lds(
                (gas_ptr)(z + (size_t)(tq * 128 + row) * 512 + s_ * 128 + sx),
                (las_ptr)(&Bq[bufi][0] + o), 16, 0, 0);
        }
    };

    f32x4 acc[4][4];
    #pragma unroll
    for (int i = 0; i < 4; ++i)
        #pragma unroll
        for (int j = 0; j < 4; ++j) acc[i][j] = (f32x4)0.f;

    STAGE(0, 0);
    __syncthreads();

    #pragma unroll
    for (int s = 0; s < 4; ++s) {
        if (s < 3) STAGE((s + 1) & 1, s + 1);   // full compute phase of latency cover
        const int cb = s & 1;
        #pragma unroll
        for (int kst = 0; kst < 2; ++kst) {
            half8 a[4], bq[4];
            #pragma unroll
            for (int i = 0; i < 4; ++i) {
                const int ar = wr * 64 + i * 16 + l16;
                a[i] = *(const half8*)(&At[cb][0] + ar * 128 + ((kst * 64 + lg * 16) ^ ((ar & 7) << 4)));
                const int br = wc * 64 + i * 16 + l16;
                bq[i] = *(const half8*)(&Bq[cb][0] + br * 128 + ((kst * 64 + lg * 16) ^ ((br & 7) << 4)));
            }
            #pragma unroll
            for (int di = 0; di < 4; ++di)
                #pragma unroll
                for (int qi = 0; qi < 4; ++qi)
                    acc[di][qi] = mfma_16x16x32(a[di], bq[qi], acc[di][qi]);
        }
        if (s < 3) __syncthreads();             // drains STAGE(s+1); last barrier elided
    }

    // ---- epilogue: transform, P write, degree partials
    const int tile = tri32(tq) + tk;
    _Float16* Pt = P + (size_t)(bm * TRI + tile) * 16384;
    float dsum[4] = {0.f, 0.f, 0.f, 0.f};
    float sqq[4];
    if (mat) {
        #pragma unroll
        for (int qi = 0; qi < 4; ++qi)
            sqq[qi] = sqb[tq * 128 + wc * 64 + qi * 16 + l16];
    }
    #pragma unroll
    for (int di = 0; di < 4; ++di) {
        const int kl = wr * 64 + di * 16 + lg * 4;
        const int kg = tk * 128 + kl;
        f32x4 sqk;
        if (mat) sqk = *(const f32x4*)(sqb + kg);
        #pragma unroll
        for (int qi = 0; qi < 4; ++qi) {
            const int qg = tq * 128 + wc * 64 + qi * 16 + l16;
            half4 hv;
            #pragma unroll
            for (int r = 0; r < 4; ++r) {
                const bool msk = (kg + r) < qg;        // causal + zero-diag
                float p;
                if (mat) p = msk ? __expf(-0.5f * (sqq[qi] + sqk[r] - 2.f * acc[di][qi][r])) : 0.f;
                else     p = msk ? fmaxf(acc[di][qi][r], 0.f) : 0.f;
                dsum[qi] += p;
                hv[r] = (_Float16)p;
            }
            *(half4*)(Pt + (size_t)(wc * 64 + qi * 16 + l16) * 128 + kl) = hv;
        }
    }
    #pragma unroll
    for (int qi = 0; qi < 4; ++qi) {
        dsum[qi] += __shfl_xor(dsum[qi], 16);
        dsum[qi] += __shfl_xor(dsum[qi], 32);
    }
    if (lg == 0) {
        #pragma unroll
        for (int qi = 0; qi < 4; ++qi)
            degpart[(size_t)(bm * TRI + tile) * 256 + wr * 128 + wc * 64 + qi * 16 + l16] = dsum[qi];
    }
}

// ---------------- deg: sum tile/wave partials (deterministic) ----------------
__global__ __launch_bounds__(128) void k_deg(const float* __restrict__ degpart,
                                             float* __restrict__ deg) {
    const int bm = blockIdx.x >> 5, tq = blockIdx.x & 31;
    const float* dp = degpart + (size_t)(bm * TRI + tri32(tq)) * 256 + threadIdx.x;
    float s = 0.f;
    for (int tk = 0; tk <= tq; ++tk)
        s += dp[(size_t)tk * 256] + dp[(size_t)tk * 256 + 128];
    deg[(size_t)bm * NN + tq * 128 + threadIdx.x] = s;
}

// ---------------- PV GEMM: O^T = V^T P^T, split-K, dbuf, 1 barrier/step ----------------
__global__ __launch_bounds__(256, 2) void k_pv(const _Float16* __restrict__ P,
                                               const _Float16* __restrict__ vT,
                                               _Float16* __restrict__ part,
                                               int CHUNK, int NCH) {
    const int dh = blockIdx.x & 1, mat = (blockIdx.x >> 1) & 1;
    int x = NCH - 1 - (blockIdx.x >> 2);     // reversed: long chunks dispatch first
    int tq = 0, cum = 0;
    for (;;) {
        const int nc = (tq + CHUNK) / CHUNK;  // ceil((tq+1)/CHUNK)
        if (x < nc) break;
        x -= nc; cum += nc; ++tq;
    }
    const int c = x;
    const int b = blockIdx.y;
    const int kt0 = c * CHUNK;
    const int ktE = (kt0 + CHUNK < tq + 1) ? kt0 + CHUNK : tq + 1;
    const int NS = (ktE - kt0) * 2;

    const int w = threadIdx.x >> 6, lane = threadIdx.x & 63;
    const int l16 = lane & 15, lg = lane >> 4;
    const int wr = w >> 1, wc = w & 1;

    __shared__ char At[2][16384], Bp[2][16384];

    const char* vTb = (const char*)(vT + (size_t)b * ND * NN);
    const char* Pbase = (const char*)(P + (size_t)((b * 2 + mat) * TRI + tri32(tq)) * 16384);

    auto STAGE = [&](int bufi, int j_) {
        const int kt = kt0 + (j_ >> 1), s = j_ & 1;
        const char* Pt = Pbase + (size_t)kt * 32768;
        const int off = threadIdx.x * 16;
        #pragma unroll
        for (int i = 0; i < 4; ++i) {
            const int o = off + i * 4096;
            const int row = o >> 7;
            const int sx = (o & 127) ^ ((row & 7) << 4);
            __builtin_amdgcn_global_load_lds(
                (gas_ptr)(vTb + (size_t)(dh * 128 + row) * (NN * 2) + (size_t)kt * 256 + s * 128 + sx),
                (las_ptr)(&At[bufi][0] + o), 16, 0, 0);
        }
        #pragma unroll
        for (int i = 0; i < 4; ++i) {
            const int o = off + i * 4096;
            const int row = o >> 7;
            const int sx = (o & 127) ^ ((row & 7) << 4);
            __builtin_amdgcn_global_load_lds(
                (gas_ptr)(Pt + (size_t)row * 256 + s * 128 + sx),
                (las_ptr)(&Bp[bufi][0] + o), 16, 0, 0);
        }
    };

    f32x4 acc[4][4];
    #pragma unroll
    for (int i = 0; i < 4; ++i)
        #pragma unroll
        for (int j = 0; j < 4; ++j) acc[i][j] = (f32x4)0.f;

    STAGE(0, 0);
    __syncthreads();

    for (int j = 0; j < NS; ++j) {
        if (j + 1 < NS) STAGE((j + 1) & 1, j + 1);
        const int cb = j & 1;
        #pragma unroll
        for (int kst = 0; kst < 2; ++kst) {
            half8 a[4], bp[4];
            #pragma unroll
            for (int i = 0; i < 4; ++i) {
                const int ar = wr * 64 + i * 16 + l16;
                a[i] = *(const half8*)(&At[cb][0] + ar * 128 + ((kst * 64 + lg * 16) ^ ((ar & 7) << 4)));
                const int br = wc * 64 + i * 16 + l16;
                bp[i] = *(const half8*)(&Bp[cb][0] + br * 128 + ((kst * 64 + lg * 16) ^ ((br & 7) << 4)));
            }
            #pragma unroll
            for (int di = 0; di < 4; ++di)
                #pragma unroll
                for (int qi = 0; qi < 4; ++qi)
                    acc[di][qi] = mfma_16x16x32(a[di], bp[qi], acc[di][qi]);
        }
        if (j + 1 < NS) __syncthreads();
    }

    _Float16* sl = part + (size_t)(((b * NCH + cum + c) * 2 + dh) * 2 + mat) * 16384;
    #pragma unroll
    for (int di = 0; di < 4; ++di) {
        const int dl = wr * 64 + di * 16 + lg * 4;
        #pragma unroll
        for (int qi = 0; qi < 4; ++qi) {
            half4 hv;
            #pragma unroll
            for (int r = 0; r < 4; ++r) hv[r] = (_Float16)acc[di][qi][r];
            *(half4*)(sl + (size_t)(wc * 64 + qi * 16 + l16) * 128 + dl) = hv;
        }
    }
}

// ---------------- combine chunk partials, normalize, emit ot ----------------
__global__ __launch_bounds__(256) void k_combine2(const _Float16* __restrict__ part,
                                                  const float* __restrict__ deg,
                                                  _Float16* __restrict__ ot,
                                                  int CHUNK, int NCH) {
    const int tq = blockIdx.x >> 1, dh = blockIdx.x & 1, b = blockIdx.y;
    int cum = 0;
    for (int t = 0; t < tq; ++t) cum += (t + CHUNK) / CHUNK;
    const int nc = (tq + CHUNK) / CHUNK;
    const float* degl = deg + (size_t)(b * 2 + 0) * NN + tq * 128;
    const float* degg = deg + (size_t)(b * 2 + 1) * NN + tq * 128;
    for (int it = 0; it < 8; ++it) {
        const int e = (it * 256 + threadIdx.x) * 8;
        const int row = e >> 7, col = e & 127;
        float s_l[8] = {0,0,0,0,0,0,0,0}, s_g[8] = {0,0,0,0,0,0,0,0};
        for (int c2 = 0; c2 < nc; ++c2) {
            const size_t base = (size_t)(((b * NCH + cum + c2) * 2 + dh) * 2) * 16384 + e;
            half8 xl = *(const half8*)(part + base);
            half8 xg = *(const half8*)(part + base + 16384);
            #pragma unroll
            for (int k = 0; k < 8; ++k) { s_l[k] += (float)xl[k]; s_g[k] += (float)xg[k]; }
        }
        const float rl = 0.9f / fmaxf(degl[row], 1e-8f);   // w_l = 1 - T_WAKE
        const float rg = 0.1f / fmaxf(degg[row], 1e-8f);   // w_g = T_WAKE
        half8 o;
        #pragma unroll
        for (int k = 0; k < 8; ++k) o[k] = (_Float16)(rl * s_l[k] + rg * s_g[k]);
        *(half8*)(ot + (size_t)(b * NN + tq * 128 + row) * ND + dh * 128 + col) = o;
    }
}

// ---------------- final @ Wo ----------------
__global__ __launch_bounds__(256) void k_out(const _Float16* __restrict__ ot,
                                             const _Float16* __restrict__ Wot,
                                             float* __restrict__ out) {
    const int w = threadIdx.x >> 6, l = threadIdx.x & 63;
    const int l16 = l & 15, lg = l >> 4;
    const int row0 = blockIdx.x * 64 + w * 16;
    f32x4 acc[16];
    gemm_core(ot, Wot, row0, l16, lg, acc);
    #pragma unroll
    for (int ct = 0; ct < 16; ++ct)
        #pragma unroll
        for (int r = 0; r < 4; ++r)
            out[(size_t)(row0 + lg * 4 + r) * ND + ct * 16 + l16] = acc[ct][r];
}

extern "C" void kernel_launch(void* const* d_in, const int* in_sizes, int n_in,
                              void* d_out, int out_size, void* d_ws, size_t ws_size,
                              hipStream_t stream) {
    const float* h  = (const float*)d_in[0];
    const float* Wl = (const float*)d_in[2];
    const float* Wg = (const float*)d_in[3];
    const float* Wv = (const float*)d_in[4];
    const float* Wo = (const float*)d_in[5];
    float* out = (float*)d_out;

    uint8_t* base = (uint8_t*)d_ws;
    size_t off = 0;
    auto alloc = [&](size_t bytes) -> void* {
        void* r = base + off;
        off = (off + bytes + 255) & ~(size_t)255;
        return r;
    };
    const size_t bnd = (size_t)NB * NN * ND;
    _Float16* h16 = (_Float16*)alloc(bnd * 2);     // reused as vT after k_proj
    _Float16* Wlt = (_Float16*)alloc(ND * ND * 2);
    _Float16* Wgt = (_Float16*)alloc(ND * ND * 2);
    _Float16* Wvt = (_Float16*)alloc(ND * ND * 2);
    _Float16* Wot = (_Float16*)alloc(ND * ND * 2);
    _Float16* zn  = (_Float16*)alloc(bnd * 2);
    _Float16* zg  = (_Float16*)alloc(bnd * 2);
    _Float16* v16 = (_Float16*)alloc(bnd * 2);
    _Float16* ot  = (_Float16*)alloc(bnd * 2);
    float*    sq  = (float*)alloc((size_t)NB * NN * 4);
    _Float16* P   = (_Float16*)alloc((size_t)NB * 2 * TRI * 16384 * 2);   // 69 MB
    float* degpart = (float*)alloc((size_t)NB * 2 * TRI * 256 * 4);       // 2.2 MB
    float* deg     = (float*)alloc((size_t)NB * 2 * NN * 4);              // 64 KB
    _Float16* vT = h16;                            // alias: h16 dead after k_proj

    // split-K chunking with ws fallback
    int CHUNK = 8, NCH = 0;
    for (;;) {
        NCH = 0;
        for (int t = 0; t < 32; ++t) NCH += (t + CHUNK) / CHUNK;
        if (off + (size_t)NB * NCH * 4 * 16384 * 2 + 256 <= ws_size || CHUNK >= 32) break;
        CHUNK *= 2;
    }
    _Float16* part = (_Float16*)alloc((size_t)NB * NCH * 4 * 16384 * 2);

    k_cvt_h<<<bnd / 4 / 256, 256, 0, stream>>>(h, h16);
    k_wt<<<dim3(ND, 4), 256, 0, stream>>>(Wl, Wg, Wv, Wo, Wlt, Wgt, Wvt, Wot);
    k_proj<<<dim3(NB * NN / 64, 3), 256, 0, stream>>>(h16, Wlt, Wgt, Wvt, zn, zg, v16, sq);
    k_tr<<<dim3(NN / 64, ND / 64, NB), 256, 0, stream>>>(v16, vT);
    k_score<<<dim3(TRI, NB, 2), 256, 0, stream>>>(zn, zg, sq, P, degpart);
    k_deg<<<NB * 2 * 32, 128, 0, stream>>>(degpart, deg);
    k_pv<<<dim3(4 * NCH, NB), 256, 0, stream>>>(P, vT, part, CHUNK, NCH);
    k_combine2<<<dim3(64, NB), 256, 0, stream>>>(part, deg, ot, CHUNK, NCH);
    k_out<<<NB * NN / 64, 256, 0, stream>>>(ot, Wot, out);
}

// Round 8
// 185.309 us; speedup vs baseline: 1.1935x; 1.0214x over previous
//
#include <hip/hip_runtime.h>
#include <cstdint>
#include <cstddef>

#define NB 2
#define NN 4096
#define ND 256
#define TRI 528   // 32*33/2 causal 128-tiles per (batch, mat)

typedef __attribute__((ext_vector_type(8))) _Float16 half8;
typedef __attribute__((ext_vector_type(4))) _Float16 half4;
typedef __attribute__((ext_vector_type(4))) float f32x4;

using gas_ptr = const __attribute__((address_space(1))) void*;
using las_ptr = __attribute__((address_space(3))) void*;

__device__ __host__ __forceinline__ int tri32(int t) { return t * (t + 1) / 2; }

__device__ __forceinline__ f32x4 mfma_16x16x32(half8 a, half8 b, f32x4 c) {
    return __builtin_amdgcn_mfma_f32_16x16x32_f16(a, b, c, 0, 0, 0);
}

// counted-vmcnt barriers: keep N VMEM ops (global_load_lds) in flight across the
// barrier; own-wave lgkmcnt(0) ensures our ds_reads are consumed before others
// may overwrite the buffer we just read.
#define BAR_V4() asm volatile("s_waitcnt vmcnt(4) lgkmcnt(0)\n\ts_barrier" ::: "memory")
#define BAR_V0() asm volatile("s_waitcnt vmcnt(0) lgkmcnt(0)\n\ts_barrier" ::: "memory")

// ---- 128-row x 64B staging side, paired-row swizzle (2 logical rows / 128B) ----
// phys(r, c) = (r>>1)*128 + ((((r&1)<<6) + c) ^ (((r>>1)&7)<<4))
__device__ __forceinline__ void stage_side(const char* __restrict__ gb, size_t rstride,
                                           char* lb) {
    #pragma unroll
    for (int i = 0; i < 2; ++i) {
        const int o = threadIdx.x * 16 + i * 4096;
        const int rp = o >> 7;
        const int uw = (o & 127) ^ ((rp & 7) << 4);
        const int r = rp * 2 + (uw >> 6);
        const int c = uw & 63;
        __builtin_amdgcn_global_load_lds((gas_ptr)(gb + (size_t)r * rstride + c),
                                         (las_ptr)(lb + o), 16, 0, 0);
    }
}

__device__ __forceinline__ half8 ldsfrag(const char* lb, int row, int lg) {
    const int rp = row >> 1;
    const int x = (((row & 1) << 6) + (lg << 4)) ^ ((rp & 7) << 4);
    return *(const half8*)(lb + rp * 128 + x);
}

// ---------------- conversions ----------------
__global__ __launch_bounds__(256) void k_cvt_h(const float* __restrict__ h,
                                               _Float16* __restrict__ h16) {
    const int i = blockIdx.x * 256 + threadIdx.x;
    f32x4 v = ((const f32x4*)h)[i];
    half4 o;
    o[0] = (_Float16)v[0]; o[1] = (_Float16)v[1];
    o[2] = (_Float16)v[2]; o[3] = (_Float16)v[3];
    ((half4*)h16)[i] = o;
}

__global__ __launch_bounds__(256) void k_wt(const float* __restrict__ W0, const float* __restrict__ W1,
                                            const float* __restrict__ W2, const float* __restrict__ W3,
                                            _Float16* __restrict__ T0, _Float16* __restrict__ T1,
                                            _Float16* __restrict__ T2, _Float16* __restrict__ T3) {
    const int m = blockIdx.y;
    const float* W = m == 0 ? W0 : m == 1 ? W1 : m == 2 ? W2 : W3;
    _Float16* T    = m == 0 ? T0 : m == 1 ? T1 : m == 2 ? T2 : T3;
    const int k = blockIdx.x, j = threadIdx.x;
    T[j * ND + k] = (_Float16)W[k * ND + j];
}

// ---------------- GEMM core (projections / output) ----------------
__device__ __forceinline__ void gemm_core(const _Float16* __restrict__ A,
                                          const _Float16* __restrict__ Bt,
                                          int row0, int l16, int lg, f32x4 acc[16]) {
    #pragma unroll
    for (int i = 0; i < 16; ++i) acc[i] = (f32x4)0.0f;
    #pragma unroll
    for (int ks = 0; ks < 8; ++ks) {
        half8 a = *(const half8*)(A + (size_t)(row0 + l16) * ND + ks * 32 + lg * 8);
        #pragma unroll
        for (int ct = 0; ct < 16; ++ct) {
            half8 b = *(const half8*)(Bt + (size_t)(ct * 16 + l16) * ND + ks * 32 + lg * 8);
            acc[ct] = mfma_16x16x32(a, b, acc[ct]);
        }
    }
}

__global__ __launch_bounds__(256) void k_proj(const _Float16* __restrict__ h16,
                                              const _Float16* __restrict__ Wlt,
                                              const _Float16* __restrict__ Wgt,
                                              const _Float16* __restrict__ Wvt,
                                              _Float16* __restrict__ zn,
                                              _Float16* __restrict__ zg,
                                              _Float16* __restrict__ v16,
                                              float* __restrict__ sq) {
    const int mode = blockIdx.y;
    const _Float16* Bt = mode == 0 ? Wlt : mode == 1 ? Wgt : Wvt;
    _Float16* o16      = mode == 0 ? zn  : mode == 1 ? zg  : v16;
    const int w = threadIdx.x >> 6, l = threadIdx.x & 63;
    const int l16 = l & 15, lg = l >> 4;
    const int row0 = blockIdx.x * 64 + w * 16;
    f32x4 acc[16];
    gemm_core(h16, Bt, row0, l16, lg, acc);

    if (mode == 2) {
        #pragma unroll
        for (int ct = 0; ct < 16; ++ct)
            #pragma unroll
            for (int r = 0; r < 4; ++r)
                o16[(size_t)(row0 + lg * 4 + r) * ND + ct * 16 + l16] = (_Float16)acc[ct][r];
        return;
    }
    float n2[4] = {0.f, 0.f, 0.f, 0.f};
    #pragma unroll
    for (int ct = 0; ct < 16; ++ct)
        #pragma unroll
        for (int r = 0; r < 4; ++r) n2[r] += acc[ct][r] * acc[ct][r];
    #pragma unroll
    for (int m = 1; m < 16; m <<= 1) {
        #pragma unroll
        for (int r = 0; r < 4; ++r) n2[r] += __shfl_xor(n2[r], m);
    }
    if (mode == 0) {
        float ri[4];
        #pragma unroll
        for (int r = 0; r < 4; ++r) ri[r] = 1.0f / fmaxf(sqrtf(n2[r]), 1e-8f);
        #pragma unroll
        for (int ct = 0; ct < 16; ++ct)
            #pragma unroll
            for (int r = 0; r < 4; ++r)
                o16[(size_t)(row0 + lg * 4 + r) * ND + ct * 16 + l16] =
                    (_Float16)(acc[ct][r] * ri[r]);
    } else {
        #pragma unroll
        for (int ct = 0; ct < 16; ++ct)
            #pragma unroll
            for (int r = 0; r < 4; ++r)
                o16[(size_t)(row0 + lg * 4 + r) * ND + ct * 16 + l16] = (_Float16)acc[ct][r];
        if (l16 == 0) {
            #pragma unroll
            for (int r = 0; r < 4; ++r) sq[row0 + lg * 4 + r] = n2[r];
        }
    }
}

// v16 [b][n][d] -> vT [b][d][n]
__global__ __launch_bounds__(256) void k_tr(const _Float16* __restrict__ v16,
                                            _Float16* __restrict__ vT) {
    __shared__ _Float16 t[64][72];
    const int b = blockIdx.z, n0 = blockIdx.x * 64, d0 = blockIdx.y * 64;
    const int tj = threadIdx.x & 63, ti = threadIdx.x >> 6;
    #pragma unroll
    for (int i = 0; i < 16; ++i)
        t[ti + i * 4][tj] = v16[(size_t)(b * NN + n0 + ti + i * 4) * ND + d0 + tj];
    __syncthreads();
    #pragma unroll
    for (int i = 0; i < 16; ++i)
        vT[(size_t)(b * ND + d0 + ti + i * 4) * NN + n0 + tj] = t[tj][ti + i * 4];
}

// ---------------- score GEMM v4: BK=32, tri-buffer, counted-vmcnt barriers ------
// grid (TRI, NB, 2). 8 steps; STAGE(s+2) issued at step top; steady barrier keeps
// vmcnt(4) (= one stage) in flight. 48 KB LDS -> 3 blocks/CU.
__global__ __launch_bounds__(256, 3) void k_score(const _Float16* __restrict__ zn,
                                                  const _Float16* __restrict__ zg,
                                                  const float* __restrict__ sqg,
                                                  _Float16* __restrict__ P,
                                                  float* __restrict__ degpart) {
    int x = blockIdx.x, tq = 0;
    while (x > tq) { x -= (tq + 1); ++tq; }
    const int tk = x;
    const int b = blockIdx.y, mat = blockIdx.z;
    const int bm = b * 2 + mat;
    const char* z = (const char*)((mat ? zg : zn) + (size_t)b * NN * ND);
    const float* sqb = sqg + (size_t)b * NN;
    const int w = threadIdx.x >> 6, lane = threadIdx.x & 63;
    const int l16 = lane & 15, lg = lane >> 4;
    const int wr = w >> 1, wc = w & 1;

    __shared__ char At[3][8192], Bq[3][8192];

    const char* zk = z + (size_t)tk * 128 * 512;
    const char* zq = z + (size_t)tq * 128 * 512;

    auto STAGE = [&](int bufi, int s_) {
        stage_side(zk + s_ * 64, 512, &At[bufi][0]);
        stage_side(zq + s_ * 64, 512, &Bq[bufi][0]);
    };

    f32x4 acc[4][4];
    #pragma unroll
    for (int i = 0; i < 4; ++i)
        #pragma unroll
        for (int j = 0; j < 4; ++j) acc[i][j] = (f32x4)0.f;

    STAGE(0, 0);
    STAGE(1, 1);
    BAR_V4();                                  // stage(0) landed; stage(1) in flight

    #pragma unroll
    for (int s = 0; s < 8; ++s) {
        if (s < 6) STAGE((s + 2) % 3, s + 2);
        const int cb = s % 3;
        half8 a[4], bq[4];
        #pragma unroll
        for (int i = 0; i < 4; ++i) {
            a[i]  = ldsfrag(&At[cb][0], wr * 64 + i * 16 + l16, lg);
            bq[i] = ldsfrag(&Bq[cb][0], wc * 64 + i * 16 + l16, lg);
        }
        #pragma unroll
        for (int di = 0; di < 4; ++di)
            #pragma unroll
            for (int qi = 0; qi < 4; ++qi)
                acc[di][qi] = mfma_16x16x32(a[di], bq[qi], acc[di][qi]);
        if (s < 6) BAR_V4();                   // stage(s+1) landed; stage(s+2) in flight
        else if (s == 6) BAR_V0();             // all stages landed
    }

    // ---- epilogue: transform, P write, degree partials
    const int tile = tri32(tq) + tk;
    _Float16* Pt = P + (size_t)(bm * TRI + tile) * 16384;
    float dsum[4] = {0.f, 0.f, 0.f, 0.f};
    float sqq[4];
    if (mat) {
        #pragma unroll
        for (int qi = 0; qi < 4; ++qi)
            sqq[qi] = sqb[tq * 128 + wc * 64 + qi * 16 + l16];
    }
    #pragma unroll
    for (int di = 0; di < 4; ++di) {
        const int kl = wr * 64 + di * 16 + lg * 4;
        const int kg = tk * 128 + kl;
        f32x4 sqk;
        if (mat) sqk = *(const f32x4*)(sqb + kg);
        #pragma unroll
        for (int qi = 0; qi < 4; ++qi) {
            const int qg = tq * 128 + wc * 64 + qi * 16 + l16;
            half4 hv;
            #pragma unroll
            for (int r = 0; r < 4; ++r) {
                const bool msk = (kg + r) < qg;        // causal + zero-diag
                float p;
                if (mat) p = msk ? __expf(-0.5f * (sqq[qi] + sqk[r] - 2.f * acc[di][qi][r])) : 0.f;
                else     p = msk ? fmaxf(acc[di][qi][r], 0.f) : 0.f;
                dsum[qi] += p;
                hv[r] = (_Float16)p;
            }
            *(half4*)(Pt + (size_t)(wc * 64 + qi * 16 + l16) * 128 + kl) = hv;
        }
    }
    #pragma unroll
    for (int qi = 0; qi < 4; ++qi) {
        dsum[qi] += __shfl_xor(dsum[qi], 16);
        dsum[qi] += __shfl_xor(dsum[qi], 32);
    }
    if (lg == 0) {
        #pragma unroll
        for (int qi = 0; qi < 4; ++qi)
            degpart[(size_t)(bm * TRI + tile) * 256 + wr * 128 + wc * 64 + qi * 16 + l16] = dsum[qi];
    }
}

// ---------------- deg: sum tile/wave partials (deterministic) ----------------
__global__ __launch_bounds__(128) void k_deg(const float* __restrict__ degpart,
                                             float* __restrict__ deg) {
    const int bm = blockIdx.x >> 5, tq = blockIdx.x & 31;
    const float* dp = degpart + (size_t)(bm * TRI + tri32(tq)) * 256 + threadIdx.x;
    float s = 0.f;
    for (int tk = 0; tk <= tq; ++tk)
        s += dp[(size_t)tk * 256] + dp[(size_t)tk * 256 + 128];
    deg[(size_t)bm * NN + tq * 128 + threadIdx.x] = s;
}

// ---------------- PV GEMM v3: BK=32, tri-buffer, counted-vmcnt barriers ----------
__global__ __launch_bounds__(256, 3) void k_pv(const _Float16* __restrict__ P,
                                               const _Float16* __restrict__ vT,
                                               _Float16* __restrict__ part,
                                               int CHUNK, int NCH) {
    const int dh = blockIdx.x & 1, mat = (blockIdx.x >> 1) & 1;
    int x = NCH - 1 - (blockIdx.x >> 2);     // reversed: long chunks dispatch first
    int tq = 0, cum = 0;
    for (;;) {
        const int nc = (tq + CHUNK) / CHUNK;  // ceil((tq+1)/CHUNK)
        if (x < nc) break;
        x -= nc; cum += nc; ++tq;
    }
    const int c = x;
    const int b = blockIdx.y;
    const int kt0 = c * CHUNK;
    const int ktE = (kt0 + CHUNK < tq + 1) ? kt0 + CHUNK : tq + 1;
    const int NS = (ktE - kt0) * 4;          // BK=32 steps

    const int w = threadIdx.x >> 6, lane = threadIdx.x & 63;
    const int l16 = lane & 15, lg = lane >> 4;
    const int wr = w >> 1, wc = w & 1;

    __shared__ char At[3][8192], Bp[3][8192];

    const char* vTb = (const char*)(vT + (size_t)b * ND * NN) + (size_t)dh * 128 * (NN * 2);
    const char* Pbase = (const char*)(P + (size_t)((b * 2 + mat) * TRI + tri32(tq)) * 16384);

    auto STAGE = [&](int bufi, int j_) {
        const int kt = kt0 + (j_ >> 2), sub = j_ & 3;
        stage_side(vTb + (size_t)kt * 256 + sub * 64, (size_t)NN * 2, &At[bufi][0]);
        stage_side(Pbase + (size_t)kt * 32768 + sub * 64, 256, &Bp[bufi][0]);
    };

    f32x4 acc[4][4];
    #pragma unroll
    for (int i = 0; i < 4; ++i)
        #pragma unroll
        for (int j = 0; j < 4; ++j) acc[i][j] = (f32x4)0.f;

    STAGE(0, 0);
    STAGE(1, 1);
    BAR_V4();

    for (int s = 0; s < NS; ++s) {
        if (s + 2 < NS) STAGE((s + 2) % 3, s + 2);
        const int cb = s % 3;
        half8 a[4], bp[4];
        #pragma unroll
        for (int i = 0; i < 4; ++i) {
            a[i]  = ldsfrag(&At[cb][0], wr * 64 + i * 16 + l16, lg);
            bp[i] = ldsfrag(&Bp[cb][0], wc * 64 + i * 16 + l16, lg);
        }
        #pragma unroll
        for (int di = 0; di < 4; ++di)
            #pragma unroll
            for (int qi = 0; qi < 4; ++qi)
                acc[di][qi] = mfma_16x16x32(a[di], bp[qi], acc[di][qi]);
        if (s + 2 < NS) BAR_V4();
        else if (s + 1 < NS) BAR_V0();
    }

    _Float16* sl = part + (size_t)(((b * NCH + cum + c) * 2 + dh) * 2 + mat) * 16384;
    #pragma unroll
    for (int di = 0; di < 4; ++di) {
        const int dl = wr * 64 + di * 16 + lg * 4;
        #pragma unroll
        for (int qi = 0; qi < 4; ++qi) {
            half4 hv;
            #pragma unroll
            for (int r = 0; r < 4; ++r) hv[r] = (_Float16)acc[di][qi][r];
            *(half4*)(sl + (size_t)(wc * 64 + qi * 16 + l16) * 128 + dl) = hv;
        }
    }
}

// ---------------- combine chunk partials, normalize, emit ot ----------------
__global__ __launch_bounds__(256) void k_combine2(const _Float16* __restrict__ part,
                                                  const float* __restrict__ deg,
                                                  _Float16* __restrict__ ot,
                                                  int CHUNK, int NCH) {
    const int tq = blockIdx.x >> 1, dh = blockIdx.x & 1, b = blockIdx.y;
    int cum = 0;
    for (int t = 0; t < tq; ++t) cum += (t + CHUNK) / CHUNK;
    const int nc = (tq + CHUNK) / CHUNK;
    const float* degl = deg + (size_t)(b * 2 + 0) * NN + tq * 128;
    const float* degg = deg + (size_t)(b * 2 + 1) * NN + tq * 128;
    for (int it = 0; it < 8; ++it) {
        const int e = (it * 256 + threadIdx.x) * 8;
        const int row = e >> 7, col = e & 127;
        float s_l[8] = {0,0,0,0,0,0,0,0}, s_g[8] = {0,0,0,0,0,0,0,0};
        for (int c2 = 0; c2 < nc; ++c2) {
            const size_t base = (size_t)(((b * NCH + cum + c2) * 2 + dh) * 2) * 16384 + e;
            half8 xl = *(const half8*)(part + base);
            half8 xg = *(const half8*)(part + base + 16384);
            #pragma unroll
            for (int k = 0; k < 8; ++k) { s_l[k] += (float)xl[k]; s_g[k] += (float)xg[k]; }
        }
        const float rl = 0.9f / fmaxf(degl[row], 1e-8f);   // w_l = 1 - T_WAKE
        const float rg = 0.1f / fmaxf(degg[row], 1e-8f);   // w_g = T_WAKE
        half8 o;
        #pragma unroll
        for (int k = 0; k < 8; ++k) o[k] = (_Float16)(rl * s_l[k] + rg * s_g[k]);
        *(half8*)(ot + (size_t)(b * NN + tq * 128 + row) * ND + dh * 128 + col) = o;
    }
}

// ---------------- final @ Wo ----------------
__global__ __launch_bounds__(256) void k_out(const _Float16* __restrict__ ot,
                                             const _Float16* __restrict__ Wot,
                                             float* __restrict__ out) {
    const int w = threadIdx.x >> 6, l = threadIdx.x & 63;
    const int l16 = l & 15, lg = l >> 4;
    const int row0 = blockIdx.x * 64 + w * 16;
    f32x4 acc[16];
    gemm_core(ot, Wot, row0, l16, lg, acc);
    #pragma unroll
    for (int ct = 0; ct < 16; ++ct)
        #pragma unroll
        for (int r = 0; r < 4; ++r)
            out[(size_t)(row0 + lg * 4 + r) * ND + ct * 16 + l16] = acc[ct][r];
}

extern "C" void kernel_launch(void* const* d_in, const int* in_sizes, int n_in,
                              void* d_out, int out_size, void* d_ws, size_t ws_size,
                              hipStream_t stream) {
    const float* h  = (const float*)d_in[0];
    const float* Wl = (const float*)d_in[2];
    const float* Wg = (const float*)d_in[3];
    const float* Wv = (const float*)d_in[4];
    const float* Wo = (const float*)d_in[5];
    float* out = (float*)d_out;

    uint8_t* base = (uint8_t*)d_ws;
    size_t off = 0;
    auto alloc = [&](size_t bytes) -> void* {
        void* r = base + off;
        off = (off + bytes + 255) & ~(size_t)255;
        return r;
    };
    const size_t bnd = (size_t)NB * NN * ND;
    _Float16* h16 = (_Float16*)alloc(bnd * 2);     // reused as vT after k_proj
    _Float16* Wlt = (_Float16*)alloc(ND * ND * 2);
    _Float16* Wgt = (_Float16*)alloc(ND * ND * 2);
    _Float16* Wvt = (_Float16*)alloc(ND * ND * 2);
    _Float16* Wot = (_Float16*)alloc(ND * ND * 2);
    _Float16* zn  = (_Float16*)alloc(bnd * 2);
    _Float16* zg  = (_Float16*)alloc(bnd * 2);
    _Float16* v16 = (_Float16*)alloc(bnd * 2);
    _Float16* ot  = (_Float16*)alloc(bnd * 2);
    float*    sq  = (float*)alloc((size_t)NB * NN * 4);
    _Float16* P   = (_Float16*)alloc((size_t)NB * 2 * TRI * 16384 * 2);   // 69 MB
    float* degpart = (float*)alloc((size_t)NB * 2 * TRI * 256 * 4);       // 2.2 MB
    float* deg     = (float*)alloc((size_t)NB * 2 * NN * 4);              // 64 KB
    _Float16* vT = h16;                            // alias: h16 dead after k_proj

    // split-K chunking with ws fallback
    int CHUNK = 8, NCH = 0;
    for (;;) {
        NCH = 0;
        for (int t = 0; t < 32; ++t) NCH += (t + CHUNK) / CHUNK;
        if (off + (size_t)NB * NCH * 4 * 16384 * 2 + 256 <= ws_size || CHUNK >= 32) break;
        CHUNK *= 2;
    }
    _Float16* part = (_Float16*)alloc((size_t)NB * NCH * 4 * 16384 * 2);

    k_cvt_h<<<bnd / 4 / 256, 256, 0, stream>>>(h, h16);
    k_wt<<<dim3(ND, 4), 256, 0, stream>>>(Wl, Wg, Wv, Wo, Wlt, Wgt, Wvt, Wot);
    k_proj<<<dim3(NB * NN / 64, 3), 256, 0, stream>>>(h16, Wlt, Wgt, Wvt, zn, zg, v16, sq);
    k_tr<<<dim3(NN / 64, ND / 64, NB), 256, 0, stream>>>(v16, vT);
    k_score<<<dim3(TRI, NB, 2), 256, 0, stream>>>(zn, zg, sq, P, degpart);
    k_deg<<<NB * 2 * 32, 128, 0, stream>>>(degpart, deg);
    k_pv<<<dim3(4 * NCH, NB), 256, 0, stream>>>(P, vT, part, CHUNK, NCH);
    k_combine2<<<dim3(64, NB), 256, 0, stream>>>(part, deg, ot, CHUNK, NCH);
    k_out<<<NB * NN / 64, 256, 0, stream>>>(ot, Wot, out);
}